// Round 1
// baseline (34.679 us; speedup 1.0000x reference)
//
#include <hip/hip_runtime.h>
#include <math.h>

// Volume rendering: R rays, N=192 samples/ray.
// One wavefront (64 lanes) per ray; lane l owns samples {l, l+64, l+128}.
// Sequential cumprod -> 3 chained wave-wide inclusive product scans.

constexpr int N_SAMP = 192;
constexpr float EPS = 1e-10f;

__global__ __launch_bounds__(256) void render_kernel(
    const float* __restrict__ rgbs,   // (R, N, 3)
    const float* __restrict__ dens,   // (R, N)
    const float* __restrict__ pts,    // (R, N, 3) -- only first 6 floats used
    float* __restrict__ out,          // (R, 3)
    int R)
{
    const int lane = threadIdx.x & 63;
    const int ray  = (blockIdx.x * blockDim.x + threadIdx.x) >> 6;
    if (ray >= R) return;

    // delta: scalar step size from ray 0, samples 0 and 1 (uniform address)
    const float dx = pts[3] - pts[0];
    const float dy = pts[4] - pts[1];
    const float dz = pts[5] - pts[2];
    const float delta = sqrtf(dx * dx + dy * dy + dz * dz);

    const float* __restrict__ d_ray   = dens + (size_t)ray * N_SAMP;
    const float* __restrict__ rgb_ray = rgbs + (size_t)ray * N_SAMP * 3;

    // alpha and transmittance factor per owned sample (coalesced loads)
    float a[3], t[3];
#pragma unroll
    for (int j = 0; j < 3; ++j) {
        const float d  = d_ray[j * 64 + lane];
        const float al = 1.0f - __expf(-d * delta);
        a[j] = al;
        t[j] = 1.0f - al + EPS;
    }

    // exclusive prefix product over sample index (the rolled transmittance),
    // then weights w = trans_excl * alpha, fused with RGB accumulation.
    float sr = 0.0f, sg = 0.0f, sb = 0.0f;
    float carry = 1.0f;  // product of all samples in previous 64-chunks
#pragma unroll
    for (int j = 0; j < 3; ++j) {
        // inclusive product scan of t[j] across 64 lanes
        float incl = t[j];
#pragma unroll
        for (int off = 1; off < 64; off <<= 1) {
            const float up = __shfl_up(incl, off, 64);
            incl *= (lane >= off) ? up : 1.0f;
        }
        // exclusive scan via shift by one lane
        float excl = __shfl_up(incl, 1, 64);
        if (lane == 0) excl = 1.0f;

        const float w = carry * excl * a[j];

        const float* __restrict__ p = rgb_ray + (size_t)(j * 64 + lane) * 3;
        sr += w * p[0];
        sg += w * p[1];
        sb += w * p[2];

        // chunk total product, broadcast from last lane
        carry *= __shfl(incl, 63, 64);
    }

    // wave reduction of the three channel sums
#pragma unroll
    for (int off = 32; off >= 1; off >>= 1) {
        sr += __shfl_down(sr, off, 64);
        sg += __shfl_down(sg, off, 64);
        sb += __shfl_down(sb, off, 64);
    }
    if (lane == 0) {
        float* o = out + (size_t)ray * 3;
        o[0] = sr;
        o[1] = sg;
        o[2] = sb;
    }
}

extern "C" void kernel_launch(void* const* d_in, const int* in_sizes, int n_in,
                              void* d_out, int out_size, void* d_ws, size_t ws_size,
                              hipStream_t stream) {
    const float* rgbs = (const float*)d_in[0];
    const float* dens = (const float*)d_in[1];
    const float* pts  = (const float*)d_in[2];
    float* out = (float*)d_out;

    const int R = in_sizes[1] / N_SAMP;  // densities is (R, N)

    const int waves_per_block = 4;       // 256 threads
    dim3 block(256);
    dim3 grid((R + waves_per_block - 1) / waves_per_block);
    render_kernel<<<grid, block, 0, stream>>>(rgbs, dens, pts, out, R);
}